// Round 10
// baseline (139.178 us; speedup 1.0000x reference)
//
#include <hip/hip_runtime.h>
#include <math.h>

#define NB 16          // images
#define NP 100         // predictions per image
#define NT 320         // total targets
#define NCLS 80        // classes
#define WO 128         // output mask width/height
#define HW 16384       // 128*128
#define QT 1600        // NB*NP
#define PI 20          // targets per image
#define KSPLIT 8
#define KSLICE 2048    // HW/KSPLIT  (same slice boundaries as r3..r9 -> bit-identical num)
#define BK 64
#define KTILES 32      // KSLICE/BK
#define SRC_W 256
#define BM 64
#define BN 160
#define CH 16          // output rows per downsample block

typedef _Float16 half4v __attribute__((ext_vector_type(4)));
typedef _Float16 half8v __attribute__((ext_vector_type(8)));
typedef float f32x4 __attribute__((ext_vector_type(4)));

#define GLOAD_LDS16(gp, lp) __builtin_amdgcn_global_load_lds(                         \
    (const __attribute__((address_space(1))) void*)(gp),                              \
    (__attribute__((address_space(3))) void*)(lp), 16, 0, 0)

__device__ __forceinline__ float sigf(float x){ return 1.0f/(1.0f+expf(-x)); }
__device__ __forceinline__ float sigfast(float x){ return 1.0f/(1.0f+__expf(-x)); }

// jax.image.resize(linear, antialias=True) 2x-downsample weights, 256 -> 128
__device__ __forceinline__ void mkw128(int i, float* w, int* ix){
  int j0 = 2*i - 1;
  ix[0]=j0; ix[1]=j0+1; ix[2]=j0+2; ix[3]=j0+3;
  w[0]=0.125f; w[1]=0.375f; w[2]=0.375f; w[3]=0.125f;
  if (i == 0){ ix[0]=0; w[0]=0.0f; w[1]=3.0f/7.0f; w[2]=3.0f/7.0f; w[3]=1.0f/7.0f; }
  if (i == 127){ ix[3]=255; w[3]=0.0f; w[0]=1.0f/7.0f; w[1]=3.0f/7.0f; w[2]=3.0f/7.0f; }
}

// K0: Ah = (fp16) sigmoid(A), fused per-row pq = sum sigmoid^2 (fp32).
__global__ __launch_bounds__(256) void k_sig(const float* __restrict__ A,
                                             _Float16* __restrict__ Ah,
                                             float* __restrict__ pq){
  const int q = blockIdx.x;
  const int tid = threadIdx.x;
  const float4* src = (const float4*)(A + (size_t)q * HW);
  half4v* dst = (half4v*)(Ah + (size_t)q * HW);
  float ss = 0.f;
  #pragma unroll
  for (int i = 0; i < 16; ++i){
    float4 v = src[i*256 + tid];
    float s0 = sigfast(v.x), s1 = sigfast(v.y), s2 = sigfast(v.z), s3 = sigfast(v.w);
    ss += s0*s0 + s1*s1 + s2*s2 + s3*s3;
    half4v hh = { (_Float16)s0, (_Float16)s1, (_Float16)s2, (_Float16)s3 };
    dst[i*256 + tid] = hh;
  }
  __shared__ float wred[4];
  for (int off = 32; off; off >>= 1) ss += __shfl_xor(ss, off);
  if ((tid & 63) == 0) wred[tid >> 6] = ss;
  __syncthreads();
  if (tid == 0) pq[q] = wred[0] + wred[1] + wred[2] + wred[3];
}

// K1: separable downsample, one block per (target, 16-row output chunk).
__global__ __launch_bounds__(256) void k_downsample(const float* __restrict__ tgt,
                                                    _Float16* __restrict__ tm,
                                                    float* __restrict__ tqpart){
  const int blk = blockIdx.x;
  const int t = blk >> 3;
  const int c = blk & 7;               // chunk: output rows [c*16, c*16+16)
  const int x = threadIdx.x;           // input column 0..255
  const int oy0 = c * CH;
  const int r0 = 2*oy0 - 1;            // first needed input row (may be -1)
  const float* src = tgt + (size_t)t * (SRC_W*SRC_W);
  __shared__ float vbuf[CH][SRC_W];
  __shared__ float wred[4];

  float cc[34];
  #pragma unroll
  for (int li = 0; li < 34; ++li){
    int r = r0 + li; r = r < 0 ? 0 : (r > 255 ? 255 : r);
    cc[li] = src[r*SRC_W + x];
  }
  #pragma unroll
  for (int dy = 0; dy < CH; ++dy){
    int oy = oy0 + dy;
    float w0=0.125f, w1=0.375f, w2=0.375f, w3=0.125f;
    if (oy == 0){ w0=0.0f; w1=3.0f/7.0f; w2=3.0f/7.0f; w3=1.0f/7.0f; }
    if (oy == 127){ w3=0.0f; w0=1.0f/7.0f; w1=3.0f/7.0f; w2=3.0f/7.0f; }
    vbuf[dy][x] = w0*cc[2*dy] + w1*cc[2*dy+1] + w2*cc[2*dy+2] + w3*cc[2*dy+3];
  }
  __syncthreads();

  float ssq = 0.f;
  _Float16* dst = tm + (size_t)t * HW + (size_t)oy0 * WO;
  #pragma unroll
  for (int i = 0; i < 8; ++i){
    int e = x + 256*i;                 // 0..2047
    int oy = e >> 7;                   // local output row 0..15
    int ox = e & 127;
    float w[4]; int ix[4];
    mkw128(ox, w, ix);
    float val = w[0]*vbuf[oy][ix[0]] + w[1]*vbuf[oy][ix[1]]
              + w[2]*vbuf[oy][ix[2]] + w[3]*vbuf[oy][ix[3]];
    dst[oy*WO + ox] = (_Float16)val;
    ssq += val*val;
  }
  for (int off=32; off; off>>=1) ssq += __shfl_xor(ssq, off);
  if ((x & 63) == 0) wred[x >> 6] = ssq;
  __syncthreads();
  if (x == 0) tqpart[c*NT + t] = wred[0]+wred[1]+wred[2]+wred[3];
}

// K3: MFMA fp16 GEMM  part[z][q][t] = sum_{k in slice z} Ah[q][k] * Tm[t][k]
// r9 geometry (BM=64 x BN=160 x BK=64, grid 25x2x8, 512 thr, 8 waves of 16x80).
// B: TRIPLE-buffered global_load_lds staged 2 tiles ahead; counted s_waitcnt
// vmcnt(5) per step (never 0 in the loop). A: direct-from-global register
// fragments (no LDS round-trip), 2-deep. Fragment/acc chain identical to r9
// -> num bit-identical.
__global__ __launch_bounds__(512, 4) void k_gemm(const _Float16* __restrict__ Ah,
                                                 const _Float16* __restrict__ Bm,
                                                 float* __restrict__ part){
  __shared__ _Float16 Bs[3][BN*BK];    // 3 x 20 KB
  const int tid = threadIdx.x;
  const int lane = tid & 63;
  const int wid = tid >> 6;            // 0..7
  const int rg = wid >> 1;             // row group 0..3  (rows rg*16..+15)
  const int cg = wid & 1;              // col group 0..1  (cols cg*80..+79)
  const int q0 = blockIdx.x * BM;
  const int t0 = blockIdx.y * BN;
  const int z  = blockIdx.z;
  const int ks = z * KSLICE;

  // A fragment source: lane owns row q0+rg*16+(lane&15); ksub chunks at +0 / +32
  const _Float16* afp = Ah + (size_t)(q0 + rg*16 + (lane & 15)) * HW + ks + ((lane >> 4) * 8);

  f32x4 acc[5];
  #pragma unroll
  for (int n = 0; n < 5; ++n) acc[n] = (f32x4){0.f,0.f,0.f,0.f};

  // ---- prologue: stage B(0), B(1); load A(0), A(1) frags; full drain once ----
  #pragma unroll
  for (int i = 0; i < 3; ++i){
    int g = i*512 + tid;               // 16B chunk 0..1279
    if (g < 1280){
      int row = g >> 3, s = g & 7;
      GLOAD_LDS16(Bm + (size_t)(t0 + row)*HW + ks + ((s ^ (row & 7)) * 8),
                  &Bs[0][(size_t)g*8]);
    }
  }
  #pragma unroll
  for (int i = 0; i < 3; ++i){
    int g = i*512 + tid;
    if (g < 1280){
      int row = g >> 3, s = g & 7;
      GLOAD_LDS16(Bm + (size_t)(t0 + row)*HW + ks + BK + ((s ^ (row & 7)) * 8),
                  &Bs[1][(size_t)g*8]);
    }
  }
  half8v aH0 = *(const half8v*)(afp);
  half8v aH1 = *(const half8v*)(afp + 32);
  half8v aC0 = *(const half8v*)(afp + BK);
  half8v aC1 = *(const half8v*)(afp + BK + 32);
  asm volatile("s_waitcnt vmcnt(0)" ::: "memory");
  __builtin_amdgcn_s_barrier();

  // ---- main loop: counted vmcnt(5), one barrier per K-step ----
  for (int kt = 0; kt < KTILES; ++kt){
    half8v aN0, aN1;
    // 1) issue B(kt+2) stage (3 vmem) + A(kt+2) frag loads (2 vmem)
    if (kt + 2 < KTILES){
      _Float16* lds = &Bs[(kt+2)%3][0];
      const _Float16* bbase = Bm + (size_t)(ks + (kt+2)*BK);
      #pragma unroll
      for (int i = 0; i < 3; ++i){
        int g = i*512 + tid;
        if (g < 1280){
          int row = g >> 3, s = g & 7;
          GLOAD_LDS16(bbase + (size_t)(t0 + row)*HW + ((s ^ (row & 7)) * 8),
                      lds + (size_t)g*8);
        }
      }
      const _Float16* apn = afp + (kt+2)*BK;
      aN0 = *(const half8v*)(apn);
      aN1 = *(const half8v*)(apn + 32);
    }
    // 2) compute tile kt from regs (A) + LDS (B): ksub 0 then 1, ascending
    {
      const _Float16* bb = &Bs[kt%3][0];
      half8v bf[5];
      #pragma unroll
      for (int n = 0; n < 5; ++n){
        int r = cg*80 + n*16 + (lane & 15);
        int c = 0*4 + (lane >> 4);
        bf[n] = *(const half8v*)&bb[r*BK + ((c ^ (r & 7)) * 8)];
      }
      #pragma unroll
      for (int n = 0; n < 5; ++n)
        acc[n] = __builtin_amdgcn_mfma_f32_16x16x32_f16(aH0, bf[n], acc[n], 0, 0, 0);
      #pragma unroll
      for (int n = 0; n < 5; ++n){
        int r = cg*80 + n*16 + (lane & 15);
        int c = 1*4 + (lane >> 4);
        bf[n] = *(const half8v*)&bb[r*BK + ((c ^ (r & 7)) * 8)];
      }
      #pragma unroll
      for (int n = 0; n < 5; ++n)
        acc[n] = __builtin_amdgcn_mfma_f32_16x16x32_f16(aH1, bf[n], acc[n], 0, 0, 0);
    }
    // 3) counted wait: leave only the 5 just-issued (kt+2) ops in flight ->
    //    B(kt+1) in LDS and A(kt+1) regs are complete for every wave.
    if (kt + 2 < KTILES){
      asm volatile("s_waitcnt vmcnt(5)" ::: "memory");
    } else {
      asm volatile("s_waitcnt vmcnt(0)" ::: "memory");
    }
    __builtin_amdgcn_s_barrier();
    // 4) rotate A registers
    aH0 = aC0; aH1 = aC1;
    if (kt + 2 < KTILES){ aC0 = aN0; aC1 = aN1; }
  }

  // write split-K partials (fp32): C/D layout col=lane&15, row=(lane>>4)*4+reg
  float* op = part + (size_t)z * (QT*NT);
  {
    int qb = q0 + rg*16 + (lane >> 4)*4;
    #pragma unroll
    for (int n = 0; n < 5; ++n){
      int t = t0 + cg*80 + n*16 + (lane & 15);
      #pragma unroll
      for (int r = 0; r < 4; ++r)
        op[(size_t)(qb + r)*NT + t] = acc[n][r];
    }
  }
}

// K4: final cost C = dice^0.8 * prob^0.2 (reduces split-K partials of num, tq)
__global__ __launch_bounds__(256) void k_cost(const float* __restrict__ part,
                                              const float* __restrict__ pq,
                                              const float* __restrict__ tqpart,
                                              const float* __restrict__ logits,
                                              const int* __restrict__ ids,
                                              float* __restrict__ Cout){
  int idx = blockIdx.x * 256 + threadIdx.x;
  int q = idx / NT;
  int t = idx - q * NT;
  float num = 0.f;
  #pragma unroll
  for (int s = 0; s < KSPLIT; ++s) num += part[(size_t)s * (QT*NT) + idx];
  num *= 2.0f;
  float tqv = 0.f;
  #pragma unroll
  for (int s = 0; s < 8; ++s) tqv += tqpart[s * NT + t];
  float den = pq[q] + tqv + 1e-4f;
  float dice = num / den;
  float prob = sigf(logits[q * NCLS + ids[t]]);
  Cout[idx] = powf(dice, 0.8f) * powf(prob, 0.2f);
}

// K5: Hungarian (JV / e-maxx with potentials), transposed: 20 rows (targets) x 100 cols (preds).
__global__ __launch_bounds__(64) void k_hung(const float* __restrict__ C,
                                             float* __restrict__ rows_out,
                                             float* __restrict__ cols_out){
  const int b = blockIdx.x;
  const int lane = threadIdx.x;
  __shared__ float negC[PI*NP];     // [i][j] = -C[b, j, b*PI + i]
  __shared__ double u[PI+1];
  __shared__ int p[NP+1];
  __shared__ int way[NP+1];
  for (int e = lane; e < PI*NP; e += 64){
    int i = e / NP, j = e - i*NP;
    negC[e] = -C[(size_t)(b*NP + j)*NT + (b*PI + i)];
  }
  if (lane <= PI) u[lane] = 0.0;
  for (int j = lane; j <= NP; j += 64){ p[j] = 0; way[j] = 0; }
  __syncthreads();
  const int jA = lane + 1;           // 1..64
  const int jB = lane + 65;          // 65..128
  const bool hasB = (jB <= NP);
  double vA = 0.0, vB = 0.0;
  const double INFD = 1e18;
  for (int i = 1; i <= PI; ++i){
    if (lane == 0) p[0] = i;
    __syncthreads();
    double mvA = INFD, mvB = INFD;
    bool usA = false, usB = false;
    int j0 = 0;
    int jbrk = 0;
    while (true){
      if (jA == j0) usA = true;
      if (hasB && jB == j0) usB = true;
      int i0 = p[j0];
      double ui0 = u[i0];
      double candA = INFD, candB = INFD;
      if (!usA){
        double cur = (double)negC[(i0-1)*NP + (jA-1)] - ui0 - vA;
        if (cur < mvA){ mvA = cur; way[jA] = j0; }
        candA = mvA;
      }
      if (hasB && !usB){
        double cur = (double)negC[(i0-1)*NP + (jB-1)] - ui0 - vB;
        if (cur < mvB){ mvB = cur; way[jB] = j0; }
        candB = mvB;
      }
      double bv; int bj;
      if (candB < candA){ bv = candB; bj = jB; } else { bv = candA; bj = jA; }
      for (int off = 32; off; off >>= 1){
        double ov = __shfl_xor(bv, off);
        int oj = __shfl_xor(bj, off);
        if (ov < bv || (ov == bv && oj < bj)){ bv = ov; bj = oj; }
      }
      const double delta = bv;
      if (usA){ int pj = p[jA]; u[pj] += delta; vA -= delta; }
      else mvA -= delta;
      if (hasB){
        if (usB){ int pj = p[jB]; u[pj] += delta; vB -= delta; }
        else mvB -= delta;
      }
      if (lane == 0) u[p[0]] += delta;   // virtual column 0 carries the new row
      __syncthreads();
      j0 = bj;
      if (p[j0] == 0){ jbrk = j0; break; }
    }
    __syncthreads();
    if (lane == 0){
      int j0a = jbrk;
      while (j0a){
        int jp = way[j0a];
        p[j0a] = p[jp];
        j0a = jp;
      }
    }
    __syncthreads();
  }
  if (lane == 0){
    int cnt = 0;
    for (int j = 1; j <= NP; ++j){
      int pi = p[j];
      if (pi != 0){
        rows_out[b*PI + cnt] = (float)(j - 1);   // prediction index, ascending
        cols_out[b*PI + cnt] = (float)(pi - 1);  // target index within image
        ++cnt;
      }
    }
  }
}

extern "C" void kernel_launch(void* const* d_in, const int* in_sizes, int n_in,
                              void* d_out, int out_size, void* d_ws, size_t ws_size,
                              hipStream_t stream){
  const float* pred_masks  = (const float*)d_in[0];
  const float* pred_logits = (const float*)d_in[1];
  const float* tgt_masks   = (const float*)d_in[2];
  const int*   tgt_ids     = (const int*)d_in[3];
  float* out = (float*)d_out;
  char* ws = (char*)d_ws;
  _Float16* Th  = (_Float16*)ws;                                    // NT*HW*2  = 10.49 MB
  size_t off = (size_t)NT*HW*2;
  float* tqpart = (float*)(ws + off);            off += 16384;      // 8*320 f32
  float* pq     = (float*)(ws + off);            off += 16384;      // 1600 f32
  _Float16* Ah  = (_Float16*)(ws + off);         off += (size_t)QT*HW*2;  // 52.43 MB
  float* part   = (float*)(ws + off);                                // 8*512000 f32 = 16.4 MB

  k_sig<<<QT, 256, 0, stream>>>(pred_masks, Ah, pq);
  k_downsample<<<NT*8, 256, 0, stream>>>(tgt_masks, Th, tqpart);
  dim3 g(QT/BM, NT/BN, KSPLIT);
  k_gemm<<<g, 512, 0, stream>>>(Ah, Th, part);
  k_cost<<<(QT*NT)/256, 256, 0, stream>>>(part, pq, tqpart, pred_logits, tgt_ids, out);
  k_hung<<<NB, 64, 0, stream>>>(out, out + (size_t)QT*NT, out + (size_t)QT*NT + NT);
}

// Round 11
// 122.953 us; speedup vs baseline: 1.1320x; 1.1320x over previous
//
#include <hip/hip_runtime.h>
#include <math.h>

#define NB 16          // images
#define NP 100         // predictions per image
#define NT 320         // total targets
#define NCLS 80        // classes
#define WO 128         // output mask width/height
#define HW 16384       // 128*128
#define QT 1600        // NB*NP
#define PI 20          // targets per image
#define KSPLIT 8
#define KSLICE 2048    // HW/KSPLIT  (same slice boundaries as r3..r9 -> bit-identical num)
#define BK 64
#define KTILES 32      // KSLICE/BK
#define SRC_W 256
#define BM 64
#define BN 160
#define CH 16          // output rows per downsample block

typedef _Float16 half4v __attribute__((ext_vector_type(4)));
typedef _Float16 half8v __attribute__((ext_vector_type(8)));
typedef float f32x4 __attribute__((ext_vector_type(4)));

#define GLOAD_LDS16(gp, lp) __builtin_amdgcn_global_load_lds(                         \
    (const __attribute__((address_space(1))) void*)(gp),                              \
    (__attribute__((address_space(3))) void*)(lp), 16, 0, 0)

__device__ __forceinline__ float sigf(float x){ return 1.0f/(1.0f+expf(-x)); }
__device__ __forceinline__ float sigfast(float x){ return 1.0f/(1.0f+__expf(-x)); }

// jax.image.resize(linear, antialias=True) 2x-downsample weights, 256 -> 128
__device__ __forceinline__ void mkw128(int i, float* w, int* ix){
  int j0 = 2*i - 1;
  ix[0]=j0; ix[1]=j0+1; ix[2]=j0+2; ix[3]=j0+3;
  w[0]=0.125f; w[1]=0.375f; w[2]=0.375f; w[3]=0.125f;
  if (i == 0){ ix[0]=0; w[0]=0.0f; w[1]=3.0f/7.0f; w[2]=3.0f/7.0f; w[3]=1.0f/7.0f; }
  if (i == 127){ ix[3]=255; w[3]=0.0f; w[0]=1.0f/7.0f; w[1]=3.0f/7.0f; w[2]=3.0f/7.0f; }
}

// K0: Ah = (fp16) sigmoid(A), fused per-row pq = sum sigmoid^2 (fp32).
__global__ __launch_bounds__(256) void k_sig(const float* __restrict__ A,
                                             _Float16* __restrict__ Ah,
                                             float* __restrict__ pq){
  const int q = blockIdx.x;
  const int tid = threadIdx.x;
  const float4* src = (const float4*)(A + (size_t)q * HW);
  half4v* dst = (half4v*)(Ah + (size_t)q * HW);
  float ss = 0.f;
  #pragma unroll
  for (int i = 0; i < 16; ++i){
    float4 v = src[i*256 + tid];
    float s0 = sigfast(v.x), s1 = sigfast(v.y), s2 = sigfast(v.z), s3 = sigfast(v.w);
    ss += s0*s0 + s1*s1 + s2*s2 + s3*s3;
    half4v hh = { (_Float16)s0, (_Float16)s1, (_Float16)s2, (_Float16)s3 };
    dst[i*256 + tid] = hh;
  }
  __shared__ float wred[4];
  for (int off = 32; off; off >>= 1) ss += __shfl_xor(ss, off);
  if ((tid & 63) == 0) wred[tid >> 6] = ss;
  __syncthreads();
  if (tid == 0) pq[q] = wred[0] + wred[1] + wred[2] + wred[3];
}

// K1: separable downsample, one block per (target, 16-row output chunk).
__global__ __launch_bounds__(256) void k_downsample(const float* __restrict__ tgt,
                                                    _Float16* __restrict__ tm,
                                                    float* __restrict__ tqpart){
  const int blk = blockIdx.x;
  const int t = blk >> 3;
  const int c = blk & 7;               // chunk: output rows [c*16, c*16+16)
  const int x = threadIdx.x;           // input column 0..255
  const int oy0 = c * CH;
  const int r0 = 2*oy0 - 1;            // first needed input row (may be -1)
  const float* src = tgt + (size_t)t * (SRC_W*SRC_W);
  __shared__ float vbuf[CH][SRC_W];
  __shared__ float wred[4];

  float cc[34];
  #pragma unroll
  for (int li = 0; li < 34; ++li){
    int r = r0 + li; r = r < 0 ? 0 : (r > 255 ? 255 : r);
    cc[li] = src[r*SRC_W + x];
  }
  #pragma unroll
  for (int dy = 0; dy < CH; ++dy){
    int oy = oy0 + dy;
    float w0=0.125f, w1=0.375f, w2=0.375f, w3=0.125f;
    if (oy == 0){ w0=0.0f; w1=3.0f/7.0f; w2=3.0f/7.0f; w3=1.0f/7.0f; }
    if (oy == 127){ w3=0.0f; w0=1.0f/7.0f; w1=3.0f/7.0f; w2=3.0f/7.0f; }
    vbuf[dy][x] = w0*cc[2*dy] + w1*cc[2*dy+1] + w2*cc[2*dy+2] + w3*cc[2*dy+3];
  }
  __syncthreads();

  float ssq = 0.f;
  _Float16* dst = tm + (size_t)t * HW + (size_t)oy0 * WO;
  #pragma unroll
  for (int i = 0; i < 8; ++i){
    int e = x + 256*i;                 // 0..2047
    int oy = e >> 7;                   // local output row 0..15
    int ox = e & 127;
    float w[4]; int ix[4];
    mkw128(ox, w, ix);
    float val = w[0]*vbuf[oy][ix[0]] + w[1]*vbuf[oy][ix[1]]
              + w[2]*vbuf[oy][ix[2]] + w[3]*vbuf[oy][ix[3]];
    dst[oy*WO + ox] = (_Float16)val;
    ssq += val*val;
  }
  for (int off=32; off; off>>=1) ssq += __shfl_xor(ssq, off);
  if ((x & 63) == 0) wred[x >> 6] = ssq;
  __syncthreads();
  if (x == 0) tqpart[c*NT + t] = wred[0]+wred[1]+wred[2]+wred[3];
}

// K3: MFMA fp16 GEMM  part[z][q][t] = sum_{k in slice z} Ah[q][k] * Tm[t][k]
// r9 body exactly (BM=64 x BN=160 x BK=64, 512 thr, 8 waves of 16x80, dbuf,
// one barrier per step), but XCD-PINNED 1D grid: id = ((x*2+y)<<3)|z, so all
// 50 blocks sharing K-slab z land on XCD z (id%8 round-robin) -> that slab's
// B working set (1.31 MB) is L2-resident; 262 MB of B re-reads become L2 hits.
// Fragment/acc chain identical to r9 -> num bit-identical.
__global__ __launch_bounds__(512, 4) void k_gemm(const _Float16* __restrict__ Ah,
                                                 const _Float16* __restrict__ Bm,
                                                 float* __restrict__ part){
  __shared__ _Float16 As[2][BM*BK];    // 2 x 8 KB
  __shared__ _Float16 Bs[2][BN*BK];    // 2 x 20 KB
  const int tid = threadIdx.x;
  const int lane = tid & 63;
  const int wid = tid >> 6;            // 0..7
  const int rg = wid >> 1;             // row group 0..3  (rows rg*16..+15)
  const int cg = wid & 1;              // col group 0..1  (cols cg*80..+79)
  const int id = blockIdx.x;
  const int z  = id & 7;               // K-slab -> XCD z (id%8 round-robin)
  const int rr = id >> 3;
  const int t0 = (rr & 1) * BN;
  const int q0 = (rr >> 1) * BM;
  const int ks = z * KSLICE;

  // staging addresses (per-thread, constant across kt up to +kt*BK)
  const int arow = tid >> 3, aslot = tid & 7;
  const _Float16* agp = Ah + (size_t)(q0 + arow)*HW + ks + ((aslot ^ (arow & 7)) * 8);

  f32x4 acc[5];
  #pragma unroll
  for (int n = 0; n < 5; ++n) acc[n] = (f32x4){0.f,0.f,0.f,0.f};

  // ---- prologue: stage A(0)+B(0) ----
  GLOAD_LDS16(agp, &As[0][(size_t)tid*8]);
  #pragma unroll
  for (int i = 0; i < 3; ++i){
    int g = i*512 + tid;               // 16B chunk 0..1279
    if (g < 1280){
      int row = g >> 3, s = g & 7;
      GLOAD_LDS16(Bm + (size_t)(t0 + row)*HW + ks + ((s ^ (row & 7)) * 8),
                  &Bs[0][(size_t)g*8]);
    }
  }
  asm volatile("s_waitcnt vmcnt(0)" ::: "memory");
  __builtin_amdgcn_s_barrier();

  // ---- main loop: ONE barrier per K-step ----
  for (int kt = 0; kt < KTILES; ++kt){
    const int cur = kt & 1, nxt = cur ^ 1;
    // 1) stage A(kt+1)+B(kt+1) into the other buffer
    if (kt + 1 < KTILES){
      GLOAD_LDS16(agp + (kt+1)*BK, &As[nxt][(size_t)tid*8]);
      #pragma unroll
      for (int i = 0; i < 3; ++i){
        int g = i*512 + tid;
        if (g < 1280){
          int row = g >> 3, s = g & 7;
          GLOAD_LDS16(Bm + (size_t)(t0 + row)*HW + ks + (kt+1)*BK + ((s ^ (row & 7)) * 8),
                      &Bs[nxt][(size_t)g*8]);
        }
      }
    }
    // 2) compute tile kt: ksub 0 then 1, ascending (chain as r9)
    #pragma unroll
    for (int s = 0; s < 2; ++s){
      half8v af, bf[5];
      {
        int r = rg*16 + (lane & 15);
        int c = s*4 + (lane >> 4);
        af = *(const half8v*)&As[cur][r*BK + ((c ^ (r & 7)) * 8)];
      }
      #pragma unroll
      for (int n = 0; n < 5; ++n){
        int r = cg*80 + n*16 + (lane & 15);
        int c = s*4 + (lane >> 4);
        bf[n] = *(const half8v*)&Bs[cur][r*BK + ((c ^ (r & 7)) * 8)];
      }
      #pragma unroll
      for (int n = 0; n < 5; ++n)
        acc[n] = __builtin_amdgcn_mfma_f32_16x16x32_f16(af, bf[n], acc[n], 0, 0, 0);
    }
    // 3) drain stages (no other VMEM outstanding), barrier
    asm volatile("s_waitcnt vmcnt(0)" ::: "memory");
    __builtin_amdgcn_s_barrier();
  }

  // write split-K partials (fp32): C/D layout col=lane&15, row=(lane>>4)*4+reg
  float* op = part + (size_t)z * (QT*NT);
  {
    int qb = q0 + rg*16 + (lane >> 4)*4;
    #pragma unroll
    for (int n = 0; n < 5; ++n){
      int t = t0 + cg*80 + n*16 + (lane & 15);
      #pragma unroll
      for (int r = 0; r < 4; ++r)
        op[(size_t)(qb + r)*NT + t] = acc[n][r];
    }
  }
}

// K4: final cost C = dice^0.8 * prob^0.2 (reduces split-K partials of num, tq)
__global__ __launch_bounds__(256) void k_cost(const float* __restrict__ part,
                                              const float* __restrict__ pq,
                                              const float* __restrict__ tqpart,
                                              const float* __restrict__ logits,
                                              const int* __restrict__ ids,
                                              float* __restrict__ Cout){
  int idx = blockIdx.x * 256 + threadIdx.x;
  int q = idx / NT;
  int t = idx - q * NT;
  float num = 0.f;
  #pragma unroll
  for (int s = 0; s < KSPLIT; ++s) num += part[(size_t)s * (QT*NT) + idx];
  num *= 2.0f;
  float tqv = 0.f;
  #pragma unroll
  for (int s = 0; s < 8; ++s) tqv += tqpart[s * NT + t];
  float den = pq[q] + tqv + 1e-4f;
  float dice = num / den;
  float prob = sigf(logits[q * NCLS + ids[t]]);
  Cout[idx] = powf(dice, 0.8f) * powf(prob, 0.2f);
}

// K5: Hungarian (JV / e-maxx with potentials), transposed: 20 rows (targets) x 100 cols (preds).
__global__ __launch_bounds__(64) void k_hung(const float* __restrict__ C,
                                             float* __restrict__ rows_out,
                                             float* __restrict__ cols_out){
  const int b = blockIdx.x;
  const int lane = threadIdx.x;
  __shared__ float negC[PI*NP];     // [i][j] = -C[b, j, b*PI + i]
  __shared__ double u[PI+1];
  __shared__ int p[NP+1];
  __shared__ int way[NP+1];
  for (int e = lane; e < PI*NP; e += 64){
    int i = e / NP, j = e - i*NP;
    negC[e] = -C[(size_t)(b*NP + j)*NT + (b*PI + i)];
  }
  if (lane <= PI) u[lane] = 0.0;
  for (int j = lane; j <= NP; j += 64){ p[j] = 0; way[j] = 0; }
  __syncthreads();
  const int jA = lane + 1;           // 1..64
  const int jB = lane + 65;          // 65..128
  const bool hasB = (jB <= NP);
  double vA = 0.0, vB = 0.0;
  const double INFD = 1e18;
  for (int i = 1; i <= PI; ++i){
    if (lane == 0) p[0] = i;
    __syncthreads();
    double mvA = INFD, mvB = INFD;
    bool usA = false, usB = false;
    int j0 = 0;
    int jbrk = 0;
    while (true){
      if (jA == j0) usA = true;
      if (hasB && jB == j0) usB = true;
      int i0 = p[j0];
      double ui0 = u[i0];
      double candA = INFD, candB = INFD;
      if (!usA){
        double cur = (double)negC[(i0-1)*NP + (jA-1)] - ui0 - vA;
        if (cur < mvA){ mvA = cur; way[jA] = j0; }
        candA = mvA;
      }
      if (hasB && !usB){
        double cur = (double)negC[(i0-1)*NP + (jB-1)] - ui0 - vB;
        if (cur < mvB){ mvB = cur; way[jB] = j0; }
        candB = mvB;
      }
      double bv; int bj;
      if (candB < candA){ bv = candB; bj = jB; } else { bv = candA; bj = jA; }
      for (int off = 32; off; off >>= 1){
        double ov = __shfl_xor(bv, off);
        int oj = __shfl_xor(bj, off);
        if (ov < bv || (ov == bv && oj < bj)){ bv = ov; bj = oj; }
      }
      const double delta = bv;
      if (usA){ int pj = p[jA]; u[pj] += delta; vA -= delta; }
      else mvA -= delta;
      if (hasB){
        if (usB){ int pj = p[jB]; u[pj] += delta; vB -= delta; }
        else mvB -= delta;
      }
      if (lane == 0) u[p[0]] += delta;   // virtual column 0 carries the new row
      __syncthreads();
      j0 = bj;
      if (p[j0] == 0){ jbrk = j0; break; }
    }
    __syncthreads();
    if (lane == 0){
      int j0a = jbrk;
      while (j0a){
        int jp = way[j0a];
        p[j0a] = p[jp];
        j0a = jp;
      }
    }
    __syncthreads();
  }
  if (lane == 0){
    int cnt = 0;
    for (int j = 1; j <= NP; ++j){
      int pi = p[j];
      if (pi != 0){
        rows_out[b*PI + cnt] = (float)(j - 1);   // prediction index, ascending
        cols_out[b*PI + cnt] = (float)(pi - 1);  // target index within image
        ++cnt;
      }
    }
  }
}

extern "C" void kernel_launch(void* const* d_in, const int* in_sizes, int n_in,
                              void* d_out, int out_size, void* d_ws, size_t ws_size,
                              hipStream_t stream){
  const float* pred_masks  = (const float*)d_in[0];
  const float* pred_logits = (const float*)d_in[1];
  const float* tgt_masks   = (const float*)d_in[2];
  const int*   tgt_ids     = (const int*)d_in[3];
  float* out = (float*)d_out;
  char* ws = (char*)d_ws;
  _Float16* Th  = (_Float16*)ws;                                    // NT*HW*2  = 10.49 MB
  size_t off = (size_t)NT*HW*2;
  float* tqpart = (float*)(ws + off);            off += 16384;      // 8*320 f32
  float* pq     = (float*)(ws + off);            off += 16384;      // 1600 f32
  _Float16* Ah  = (_Float16*)(ws + off);         off += (size_t)QT*HW*2;  // 52.43 MB
  float* part   = (float*)(ws + off);                                // 8*512000 f32 = 16.4 MB

  k_sig<<<QT, 256, 0, stream>>>(pred_masks, Ah, pq);
  k_downsample<<<NT*8, 256, 0, stream>>>(tgt_masks, Th, tqpart);
  k_gemm<<<50*KSPLIT, 512, 0, stream>>>(Ah, Th, part);
  k_cost<<<(QT*NT)/256, 256, 0, stream>>>(part, pq, tqpart, pred_logits, tgt_ids, out);
  k_hung<<<NB, 64, 0, stream>>>(out, out + (size_t)QT*NT, out + (size_t)QT*NT + NT);
}